// Round 11
// baseline (310.333 us; speedup 1.0000x reference)
//
#include <hip/hip_runtime.h>
#include <hip/hip_bf16.h>

#define NB_ 32
#define LL_ 3
#define EE_ 65536
#define NODES_ 4096
#define SLOTS_ 524288   // NODES_ * 128
#define NEGV -1e9f

typedef _Float16 f16x8 __attribute__((ext_vector_type(8)));
typedef float f32x4 __attribute__((ext_vector_type(4)));

// order-preserving float->uint key (max over keys == max over floats)
__device__ __forceinline__ unsigned fkey(float f) {
  unsigned b = __float_as_uint(f);
  unsigned m = ((int)b >> 31) | 0x80000000u;
  return b ^ m;
}
__device__ __forceinline__ float funkey(unsigned k) {
  unsigned xm = (k & 0x80000000u) ? 0x80000000u : 0xFFFFFFFFu;
  return __uint_as_float(k ^ xm);
}

// ---------------- fused prologue: node_enc | wprep | bembWe | edge_count+rank
// blocks [0,2048): node encoder (2 nodes/block) -> zh f16 [4096][256]
// blocks [2048,2264): weight prep -> Whf fragment-major fp16 (55296 f16x8)
// blocks [2264,2336): bembWeh = f16(bond_emb @ We[l]) for 3 layers (2 rows/blk)
// blocks [2336,2592): edge histogram + per-edge rank
// Whf layout (f16x8 units), B-frag: lane l holds col=ct*16+(l&15), k=kt*32+(l>>4)*8+e
//   [0,12288):      Wp1/Wp2  mat=lyr*2+which, frag (ct*4+kt)*64+lane
//   [12288,36864):  Wm12 (col<128:Wm1 else Wm2), per layer 8192, (ct*8+kt)*64+lane
//   [36864,55296):  Wo12 (k<256:Wo1 else Wo2), per layer 6144, (ct*12+kt)*64+lane
__global__ __launch_bounds__(256) void k_pro(const int* __restrict__ x,
    const float* __restrict__ atom_emb, _Float16* __restrict__ zh,
    const float* __restrict__ Wp1, const float* __restrict__ Wp2,
    const float* __restrict__ Wm1, const float* __restrict__ Wm2,
    const float* __restrict__ Wo1, const float* __restrict__ Wo2,
    _Float16* __restrict__ Whf,
    const float* __restrict__ bond_emb, const float* __restrict__ We,
    _Float16* __restrict__ bembWeh,
    const int* __restrict__ ei, int* __restrict__ cnt, int* __restrict__ erank) {
  int blk = blockIdx.x, tid = threadIdx.x;
  if (blk < 2048) {
    int v = blk * 2 + (tid >> 7), t = tid & 127;
    float acc = 0.f;
#pragma unroll
    for (int c = 0; c < 9; c++) {
      int xv = x[v * 9 + c];
      acc += atom_emb[(c * 128 + xv) * 128 + t];
    }
    zh[v * 256 + t] = (_Float16)acc;
    zh[v * 256 + 128 + t] = (_Float16)0.f;
  } else if (blk < 2264) {
    int gid = (blk - 2048) * 256 + tid;   // 0..55295
    int lane = gid & 63;
    int llo = lane & 15, lhi = lane >> 4;
    const float* W; int col, kbase;
    if (gid < 12288) {
      int mat = gid >> 11, pos = gid & 2047;
      int fr = pos >> 6; int ct = fr >> 2, kt = fr & 3;
      int lyr = mat >> 1, which = mat & 1;
      W = (which ? Wp2 : Wp1) + lyr * 16384;
      col = ct * 16 + llo; kbase = kt * 32 + lhi * 8;
    } else if (gid < 36864) {
      int q = gid - 12288;
      int lyr = q >> 13, r = q & 8191;
      int fr = r >> 6; int ct = fr >> 3, kt = fr & 7;
      col = ct * 16 + llo; kbase = kt * 32 + lhi * 8;
      if (col < 128) { W = Wm1 + lyr * 32768; }
      else { W = Wm2 + lyr * 32768; col -= 128; }
    } else {
      int q = gid - 36864;
      int lyr = q / 6144, r = q % 6144;
      int fr = r >> 6; int ct = fr / 12, kt = fr % 12;
      col = ct * 16 + llo; kbase = kt * 32 + lhi * 8;
      if (kbase < 256) { W = Wo1 + lyr * 32768; }
      else { W = Wo2 + lyr * 16384; kbase -= 256; }
    }
    f16x8 h;
#pragma unroll
    for (int e = 0; e < 8; e++) h[e] = (_Float16)W[(kbase + e) * 128 + col];
    ((f16x8*)Whf)[gid] = h;
  } else if (blk < 2336) {
    __shared__ float row[2][128];
    int rid = (blk - 2264) * 2 + (tid >> 7);   // 0..143
    int half = tid >> 7, c = tid & 127;
    int l = rid / 48, rr = rid % 48;
    row[half][c] = bond_emb[rr * 128 + c];
    __syncthreads();
    const float* W = We + l * 16384;
    float acc = 0.f;
    for (int k = 0; k < 128; k += 4) {
      acc += row[half][k] * W[k * 128 + c] +
             row[half][k + 1] * W[(k + 1) * 128 + c] +
             row[half][k + 2] * W[(k + 2) * 128 + c] +
             row[half][k + 3] * W[(k + 3) * 128 + c];
    }
    bembWeh[(l * 48 + rr) * 128 + c] = (_Float16)acc;
  } else {
    int e = (blk - 2336) * 256 + tid;
    int s = ei[e], d = ei[EE_ + e];
    int g = s >> 7, i = s & 127, j = d & 127;
    int slot = ((g << 7) + j) * 128 + i;   // receiver-major
    erank[e] = atomicAdd(&cnt[slot], 1);
  }
}

// ---------------- fused scan: per-block scans + last-block top-level scan
__global__ __launch_bounds__(256) void k_scanA2(const int* __restrict__ cnt,
    int* __restrict__ basep, int* __restrict__ pairbase,
    int* __restrict__ bsumA, int* __restrict__ bsumF, int* __restrict__ done) {
  __shared__ int sA[256], sF[256];
  __shared__ int elect;
  int t = threadIdx.x, blk = blockIdx.x, gid = blk * 256 + t;
  int v = cnt[gid];
  int f = v > 0 ? 1 : 0;
  sA[t] = v; sF[t] = f; __syncthreads();
  for (int st = 1; st < 256; st <<= 1) {
    int aA = sA[t], aF = sF[t];
    int bA = (t >= st) ? sA[t - st] : 0;
    int bF = (t >= st) ? sF[t - st] : 0;
    __syncthreads();
    sA[t] = aA + bA; sF[t] = aF + bF;
    __syncthreads();
  }
  basep[gid] = sA[t] - v;          // exclusive within block
  pairbase[gid] = sF[t] - f;
  if (t == 255) {
    atomicExch(&bsumA[blk], sA[255]);   // device-scope atomic publish
    atomicExch(&bsumF[blk], sF[255]);
  }
  __syncthreads();
  if (t == 0) {
    __threadfence();
    elect = (atomicAdd(done, 1) == 2047) ? 1 : 0;
  }
  __syncthreads();
  if (!elect) return;
  // last block: top-level scan of the 2048 block sums (both arrays)
  __threadfence();
  int vA[8], vF[8]; int totA = 0, totF = 0;
#pragma unroll
  for (int q = 0; q < 8; q++) {
    vA[q] = atomicAdd(&bsumA[t * 8 + q], 0); totA += vA[q];
    vF[q] = atomicAdd(&bsumF[t * 8 + q], 0); totF += vF[q];
  }
  sA[t] = totA; sF[t] = totF; __syncthreads();
  for (int st = 1; st < 256; st <<= 1) {
    int aA = sA[t], aF = sF[t];
    int bA = (t >= st) ? sA[t - st] : 0;
    int bF = (t >= st) ? sF[t - st] : 0;
    __syncthreads();
    sA[t] = aA + bA; sF[t] = aF + bF;
    __syncthreads();
  }
  int runA = sA[t] - totA, runF = sF[t] - totF;
#pragma unroll
  for (int q = 0; q < 8; q++) {
    int tA = vA[q]; bsumA[t * 8 + q] = runA; runA += tA;
    int tF = vF[q]; bsumF[t * 8 + q] = runF; runF += tF;
  }
}

// ---------------- merged finalize: pair arrays | edge scatter | m12(l=0)+msgs
__global__ __launch_bounds__(256) void k_scanBSm12(const int* __restrict__ cnt,
    const int* __restrict__ basep, const int* __restrict__ pairbase,
    const int* __restrict__ bsumA, const int* __restrict__ bsumF,
    int* __restrict__ pair_total, int* __restrict__ pair_slot,
    int* __restrict__ pair_off, int* __restrict__ pair_cnt,
    const int* __restrict__ ei, const int* __restrict__ erank,
    int* __restrict__ sorted_e,
    const _Float16* __restrict__ zh, const _Float16* __restrict__ Whf,
    const float* __restrict__ bm1, const float* __restrict__ bm2,
    _Float16* __restrict__ mm, unsigned* __restrict__ msgs_u) {
  int blk = blockIdx.x, tid = threadIdx.x;
  if (blk < 2048) {
    int gid = blk * 256 + tid;
    int b = basep[gid] + bsumA[gid >> 8];
    int pb = pairbase[gid] + bsumF[gid >> 8];
    int c = cnt[gid];
    if (c > 0) {
      pair_slot[pb] = gid;
      pair_off[pb] = b;
      pair_cnt[pb] = c;
    }
    if (gid == SLOTS_ - 1) pair_total[0] = pb + (c > 0 ? 1 : 0);
  } else if (blk < 2304) {
    int e = (blk - 2048) * 256 + tid;
    int s = ei[e], d = ei[EE_ + e];
    int g = s >> 7, i = s & 127, j = d & 127;
    int slot = ((g << 7) + j) * 128 + i;
    int pos = basep[slot] + bsumA[slot >> 8] + erank[e];
    sorted_e[pos] = e;
  } else {
    int mblk = blk - 2304;                 // 0..1023: m12 for layer 0
    {  // msgs init for layer 0
      int g0 = mblk * 256 + tid;
      unsigned kneg = fkey(NEGV);
      msgs_u[g0] = kneg;
      msgs_u[g0 + 262144] = kneg;
    }
    int wv = tid >> 6, l64 = tid & 63;
    int llo = l64 & 15, lhi = l64 >> 4;
    int tile = mblk >> 2;
    int ct = (mblk & 3) * 4 + wv;          // 0..15
    int row = tile * 16 + llo;
    f16x8 a[8];
#pragma unroll
    for (int kt = 0; kt < 8; kt++)
      a[kt] = *(const f16x8*)(zh + row * 256 + kt * 32 + lhi * 8);
    const f16x8* Bf = (const f16x8*)Whf + 12288;   // layer 0
    int col = ct * 16 + llo;
    float bv = (col < 128) ? bm1[col] : bm2[col - 128];
    f32x4 acc = {bv, bv, bv, bv};
#pragma unroll
    for (int kt = 0; kt < 8; kt++)
      acc = __builtin_amdgcn_mfma_f32_16x16x32_f16(a[kt], Bf[(ct * 8 + kt) * 64 + l64], acc, 0, 0, 0);
#pragma unroll
    for (int reg = 0; reg < 4; reg++)
      mm[(tile * 16 + lhi * 4 + reg) * 256 + col] = (_Float16)acc[reg];
  }
}

// ---------------- MFMA pair MLP: 64 pairs/block, wave-shfl run scan,
// LDS receiver-tile seg-max
__global__ __launch_bounds__(256, 4) void k_pairs(
    const _Float16* __restrict__ mm,
    const int* __restrict__ pair_slot, const int* __restrict__ pair_off,
    const int* __restrict__ pair_cnt, const int* __restrict__ pair_total,
    const int* __restrict__ sorted_e, const int* __restrict__ edge_attr,
    const _Float16* __restrict__ bembWeh,
    const float* __restrict__ be, const float* __restrict__ bg,
    const _Float16* __restrict__ Whf,
    const float* __restrict__ bp1, const float* __restrict__ bp2,
    unsigned* __restrict__ msgs_u, int l) {
  __shared__ int s_slot[64], s_off[64], s_cnt[64], s_lrow[64];
  __shared__ int s_rid[16];
  __shared__ int s_nrecv;
  __shared__ unsigned Lmax[16 * 128];   // 8 KB receiver-tile max
  __shared__ _Float16 Uh[64 * 128];     // granule-XOR swizzled, 16 KB
  int P = pair_total[0];
  int pid0 = blockIdx.x * 64;
  if (pid0 >= P) return;
  int tid = threadIdx.x;
  {
    unsigned kneg = fkey(NEGV);
#pragma unroll
    for (int q = 0; q < 8; q++) Lmax[tid + q * 256] = kneg;
  }
  // wave 0 does the whole setup in-register (shfl), ONE block barrier total
  if (tid < 64) {
    int pid = pid0 + tid;
    bool va = pid < P;
    int slot = va ? pair_slot[pid] : -1;
    s_slot[tid] = slot;
    s_off[tid] = va ? pair_off[pid] : 0;
    s_cnt[tid] = va ? pair_cnt[pid] : 0;
    int r = slot >= 0 ? (slot >> 7) : -1;
    int ps = __shfl_up(slot, 1, 64);
    int pr = (tid == 0) ? -2 : (ps >= 0 ? (ps >> 7) : -1);
    int flag = (slot >= 0 && r != pr) ? 1 : 0;
    int val = flag;
#pragma unroll
    for (int d = 1; d < 64; d <<= 1) {
      int o = __shfl_up(val, d, 64);
      if (tid >= d) val += o;
    }
    int lr = val - 1;
    s_lrow[tid] = lr;
    if (flag && lr < 16) s_rid[lr] = r;
    if (tid == 63) s_nrecv = val;
  }
  __syncthreads();

  int l64 = tid & 63, wv = tid >> 6;
  int llo = l64 & 15, lhi = l64 >> 4;
  int p = wv * 16 + llo;
  int slot = s_slot[p];
  f16x8 a[4];
  if (slot >= 0) {
    int rr = slot >> 7, i = slot & 127, g = slot >> 14;
    int sn = (g << 7) + i;
    float t32[4][8];
#pragma unroll
    for (int kt = 0; kt < 4; kt++) {
      int c0 = kt * 32 + lhi * 8;
      f16x8 v1 = *(const f16x8*)(mm + sn * 256 + c0);         // m1[sender]
      f16x8 v2 = *(const f16x8*)(mm + rr * 256 + 128 + c0);   // m2[receiver]
      float4 e0 = *(const float4*)(be + l * 128 + c0);
      float4 e1 = *(const float4*)(be + l * 128 + c0 + 4);
      float4 g0 = *(const float4*)(bg + l * 128 + c0);
      float4 g1 = *(const float4*)(bg + l * 128 + c0 + 4);
      t32[kt][0] = (float)v1[0] + (float)v2[0] + e0.x + g0.x;
      t32[kt][1] = (float)v1[1] + (float)v2[1] + e0.y + g0.y;
      t32[kt][2] = (float)v1[2] + (float)v2[2] + e0.z + g0.z;
      t32[kt][3] = (float)v1[3] + (float)v2[3] + e0.w + g0.w;
      t32[kt][4] = (float)v1[4] + (float)v2[4] + e1.x + g1.x;
      t32[kt][5] = (float)v1[5] + (float)v2[5] + e1.y + g1.y;
      t32[kt][6] = (float)v1[6] + (float)v2[6] + e1.z + g1.z;
      t32[kt][7] = (float)v1[7] + (float)v2[7] + e1.w + g1.w;
    }
    int off = s_off[p], cn = s_cnt[p];
    for (int d = 0; d < cn; d++) {
      int eid = sorted_e[off + d];
      int a0 = edge_attr[eid * 3], a1 = edge_attr[eid * 3 + 1],
          a2 = edge_attr[eid * 3 + 2];
      const _Float16* r0 = bembWeh + (l * 48 + a0) * 128;
      const _Float16* r1 = bembWeh + (l * 48 + 16 + a1) * 128;
      const _Float16* r2 = bembWeh + (l * 48 + 32 + a2) * 128;
#pragma unroll
      for (int kt = 0; kt < 4; kt++) {
        int c0 = kt * 32 + lhi * 8;
        f16x8 x0 = *(const f16x8*)(r0 + c0);
        f16x8 x1 = *(const f16x8*)(r1 + c0);
        f16x8 x2 = *(const f16x8*)(r2 + c0);
#pragma unroll
        for (int e = 0; e < 8; e++)
          t32[kt][e] += (float)x0[e] + (float)x1[e] + (float)x2[e];
      }
    }
#pragma unroll
    for (int kt = 0; kt < 4; kt++)
#pragma unroll
      for (int e = 0; e < 8; e++) a[kt][e] = (_Float16)fmaxf(t32[kt][e], 0.f);
  } else {
#pragma unroll
    for (int kt = 0; kt < 4; kt++)
#pragma unroll
      for (int e = 0; e < 8; e++) a[kt][e] = (_Float16)0.f;
  }

  const f16x8* W1f = (const f16x8*)Whf + (l * 2) * 2048;
  const f16x8* W2f = (const f16x8*)Whf + (l * 2 + 1) * 2048;
  // ---- phase 1: U = relu(T @ Wp1 + bp1) -> swizzled f16 LDS
#pragma unroll
  for (int ct = 0; ct < 8; ct++) {
    int col = ct * 16 + llo;
    float b1 = bp1[l * 128 + col];
    f32x4 acc = {b1, b1, b1, b1};
#pragma unroll
    for (int kt = 0; kt < 4; kt++)
      acc = __builtin_amdgcn_mfma_f32_16x16x32_f16(a[kt], W1f[(ct * 4 + kt) * 64 + l64], acc, 0, 0, 0);
#pragma unroll
    for (int reg = 0; reg < 4; reg++) {
      int wrow = wv * 16 + lhi * 4 + reg;
      int sg = (2 * ct + (llo >> 3)) ^ (wrow & 15);
      Uh[wrow * 128 + sg * 8 + (llo & 7)] = (_Float16)fmaxf(acc[reg], 0.f);
    }
  }
  __syncthreads();
  // ---- phase 2: V = U @ Wp2 + bp2 ; LDS receiver-tile seg-max
  f16x8 a2[4];
  int arow = wv * 16 + llo;
#pragma unroll
  for (int kt = 0; kt < 4; kt++) {
    int sg = (kt * 4 + lhi) ^ (arow & 15);
    a2[kt] = *(const f16x8*)(Uh + arow * 128 + sg * 8);
  }
#pragma unroll
  for (int ct = 0; ct < 8; ct++) {
    int col = ct * 16 + llo;
    float b2 = bp2[l * 128 + col];
    f32x4 acc = {b2, b2, b2, b2};
#pragma unroll
    for (int kt = 0; kt < 4; kt++)
      acc = __builtin_amdgcn_mfma_f32_16x16x32_f16(a2[kt], W2f[(ct * 4 + kt) * 64 + l64], acc, 0, 0, 0);
    int prev_lr = -2, prev_rr = -1; float run = 0.f;
#pragma unroll
    for (int reg = 0; reg < 4; reg++) {
      int prow = wv * 16 + lhi * 4 + reg;
      int slot2 = s_slot[prow];
      if (slot2 < 0) continue;
      int lr = s_lrow[prow];
      float v = acc[reg];
      if (lr == prev_lr) {
        run = fmaxf(run, v);
      } else {
        if (prev_lr >= 0) {
          if (prev_lr < 16) atomicMax(&Lmax[prev_lr * 128 + col], fkey(run));
          else atomicMax(&msgs_u[prev_rr * 128 + col], fkey(run));
        }
        prev_lr = lr; prev_rr = slot2 >> 7; run = v;
      }
    }
    if (prev_lr >= 0) {
      if (prev_lr < 16) atomicMax(&Lmax[prev_lr * 128 + col], fkey(run));
      else atomicMax(&msgs_u[prev_rr * 128 + col], fkey(run));
    }
  }
  __syncthreads();
  // ---- flush receiver tile: one global atomic per (receiver, col) per block
  int nr = s_nrecv; if (nr > 16) nr = 16;
  for (int base = 0; base < nr; base += 2) {
    int lr = base + (tid >> 7);
    int col = tid & 127;
    if (lr < nr)
      atomicMax(&msgs_u[s_rid[lr] * 128 + col], Lmax[lr * 128 + col]);
  }
}

// ---------------- fused out_ln(l) + msgs re-init + m12(l+1)
__global__ __launch_bounds__(512, 2) void k_olnm12(_Float16* __restrict__ zh,
    unsigned* __restrict__ msgs_u, const _Float16* __restrict__ Whf,
    const float* __restrict__ bo1, const float* __restrict__ bo2,
    const float* __restrict__ ln_s, const float* __restrict__ ln_b,
    const float* __restrict__ bm1, const float* __restrict__ bm2,
    _Float16* __restrict__ mm, int l) {
  __shared__ float sumA[8][16];
  __shared__ float muS[16], rsS[16];
  __shared__ _Float16 hidT[16][132];    // +4 pad: kills stride-256B bank conflict
  int tid = threadIdx.x;
  int wv = tid >> 6, l64 = tid & 63;      // wv = ct (phase A)
  int llo = l64 & 15, lhi = l64 >> 4;
  int row = blockIdx.x * 16 + llo;
  f16x8 a[12];
#pragma unroll
  for (int kt = 0; kt < 8; kt++)
    a[kt] = *(const f16x8*)(zh + row * 256 + kt * 32 + lhi * 8);
#pragma unroll
  for (int kt = 8; kt < 12; kt++) {
    int k0 = (kt - 8) * 32 + lhi * 8;
    f16x8 h;
#pragma unroll
    for (int e = 0; e < 8; e++) {
      float v = funkey(msgs_u[row * 128 + k0 + e]);
      v = fmaxf(fminf(v, 60000.f), -60000.f);   // f16-safe (isolated-recv NEG)
      h[e] = (_Float16)v;
    }
    a[kt] = h;
  }
  const f16x8* Bo = (const f16x8*)Whf + 36864 + l * 6144;
  int ct = wv, col = ct * 16 + llo;
  float bv = bo1[l * 128 + col] + bo2[l * 128 + col];
  f32x4 acc = {bv, bv, bv, bv};
#pragma unroll
  for (int kt = 0; kt < 12; kt++)
    acc = __builtin_amdgcn_mfma_f32_16x16x32_f16(a[kt], Bo[(ct * 12 + kt) * 64 + l64], acc, 0, 0, 0);
  float h[4];
#pragma unroll
  for (int reg = 0; reg < 4; reg++) h[reg] = fmaxf(acc[reg], 0.f);
  // mean: reduce over llo lanes, then across 8 ct-waves via LDS
#pragma unroll
  for (int reg = 0; reg < 4; reg++) {
    float s = h[reg];
    s += __shfl_xor(s, 1, 64); s += __shfl_xor(s, 2, 64);
    s += __shfl_xor(s, 4, 64); s += __shfl_xor(s, 8, 64);
    if (llo == 0) sumA[wv][lhi * 4 + reg] = s;
  }
  __syncthreads();
  if (tid < 16) {
    float s = 0.f;
#pragma unroll
    for (int w = 0; w < 8; w++) s += sumA[w][tid];
    muS[tid] = s * (1.f / 128.f);
  }
  __syncthreads();
#pragma unroll
  for (int reg = 0; reg < 4; reg++) {
    float d = h[reg] - muS[lhi * 4 + reg];
    float s = d * d;
    s += __shfl_xor(s, 1, 64); s += __shfl_xor(s, 2, 64);
    s += __shfl_xor(s, 4, 64); s += __shfl_xor(s, 8, 64);
    if (llo == 0) sumA[wv][lhi * 4 + reg] = s;
  }
  __syncthreads();
  if (tid < 16) {
    float s = 0.f;
#pragma unroll
    for (int w = 0; w < 8; w++) s += sumA[w][tid];
    rsS[tid] = rsqrtf(s * (1.f / 128.f) + 1e-5f);
  }
  __syncthreads();
  float sc = ln_s[l * 128 + col], bb = ln_b[l * 128 + col];
#pragma unroll
  for (int reg = 0; reg < 4; reg++) {
    int rr = lhi * 4 + reg;
    int wrow = blockIdx.x * 16 + rr;
    _Float16 hh = (_Float16)((h[reg] - muS[rr]) * rsS[rr] * sc + bb);
    zh[wrow * 256 + 128 + col] = hh;
    hidT[rr][col] = hh;
  }
  {  // msgs re-init for this block's 16 rows (all reads done)
    unsigned kneg = fkey(NEGV);
    int base = blockIdx.x * 2048 + tid;
    msgs_u[base] = kneg;
    msgs_u[base + 512] = kneg;
    msgs_u[base + 1024] = kneg;
    msgs_u[base + 1536] = kneg;
  }
  __syncthreads();
  // ---- phase B: m12 for layer l+1 on the same 16 rows
  f16x8 b[4];
#pragma unroll
  for (int kt = 0; kt < 4; kt++)
    b[kt] = *(const f16x8*)(&hidT[llo][kt * 32 + lhi * 8]);
  const f16x8* Bm = (const f16x8*)Whf + 12288 + (l + 1) * 8192;
#pragma unroll
  for (int q = 0; q < 2; q++) {
    int ct2 = wv + q * 8;     // 0..15
    int col2 = ct2 * 16 + llo;
    float bv2 = (col2 < 128) ? bm1[(l + 1) * 128 + col2]
                             : bm2[(l + 1) * 128 + col2 - 128];
    f32x4 acc2 = {bv2, bv2, bv2, bv2};
#pragma unroll
    for (int kt = 0; kt < 4; kt++)
      acc2 = __builtin_amdgcn_mfma_f32_16x16x32_f16(a[kt], Bm[(ct2 * 8 + kt) * 64 + l64], acc2, 0, 0, 0);
#pragma unroll
    for (int kt = 0; kt < 4; kt++)
      acc2 = __builtin_amdgcn_mfma_f32_16x16x32_f16(b[kt], Bm[(ct2 * 8 + 4 + kt) * 64 + l64], acc2, 0, 0, 0);
#pragma unroll
    for (int reg = 0; reg < 4; reg++)
      mm[(blockIdx.x * 16 + lhi * 4 + reg) * 256 + col2] = (_Float16)acc2[reg];
  }
}

// ---------------- final out_ln (layer 2): h + LN -> zh hidden half
__global__ __launch_bounds__(512, 2) void k_out_ln(_Float16* __restrict__ zh,
    const unsigned* __restrict__ msgs_u, const _Float16* __restrict__ Whf,
    const float* __restrict__ bo1, const float* __restrict__ bo2,
    const float* __restrict__ ln_s, const float* __restrict__ ln_b, int l) {
  __shared__ float sumA[8][16];
  __shared__ float muS[16], rsS[16];
  int tid = threadIdx.x;
  int wv = tid >> 6, l64 = tid & 63;      // wv = ct
  int llo = l64 & 15, lhi = l64 >> 4;
  int row = blockIdx.x * 16 + llo;
  f16x8 a[12];
#pragma unroll
  for (int kt = 0; kt < 8; kt++)
    a[kt] = *(const f16x8*)(zh + row * 256 + kt * 32 + lhi * 8);
#pragma unroll
  for (int kt = 8; kt < 12; kt++) {
    int k0 = (kt - 8) * 32 + lhi * 8;
    f16x8 h;
#pragma unroll
    for (int e = 0; e < 8; e++) {
      float v = funkey(msgs_u[row * 128 + k0 + e]);
      v = fmaxf(fminf(v, 60000.f), -60000.f);
      h[e] = (_Float16)v;
    }
    a[kt] = h;
  }
  const f16x8* Bf = (const f16x8*)Whf + 36864 + l * 6144;
  int ct = wv, col = ct * 16 + llo;
  float bv = bo1[l * 128 + col] + bo2[l * 128 + col];
  f32x4 acc = {bv, bv, bv, bv};
#pragma unroll
  for (int kt = 0; kt < 12; kt++)
    acc = __builtin_amdgcn_mfma_f32_16x16x32_f16(a[kt], Bf[(ct * 12 + kt) * 64 + l64], acc, 0, 0, 0);
  float h[4];
#pragma unroll
  for (int reg = 0; reg < 4; reg++) h[reg] = fmaxf(acc[reg], 0.f);
#pragma unroll
  for (int reg = 0; reg < 4; reg++) {
    float s = h[reg];
    s += __shfl_xor(s, 1, 64); s += __shfl_xor(s, 2, 64);
    s += __shfl_xor(s, 4, 64); s += __shfl_xor(s, 8, 64);
    if (llo == 0) sumA[wv][lhi * 4 + reg] = s;
  }
  __syncthreads();
  if (tid < 16) {
    float s = 0.f;
#pragma unroll
    for (int w = 0; w < 8; w++) s += sumA[w][tid];
    muS[tid] = s * (1.f / 128.f);
  }
  __syncthreads();
#pragma unroll
  for (int reg = 0; reg < 4; reg++) {
    float d = h[reg] - muS[lhi * 4 + reg];
    float s = d * d;
    s += __shfl_xor(s, 1, 64); s += __shfl_xor(s, 2, 64);
    s += __shfl_xor(s, 4, 64); s += __shfl_xor(s, 8, 64);
    if (llo == 0) sumA[wv][lhi * 4 + reg] = s;
  }
  __syncthreads();
  if (tid < 16) {
    float s = 0.f;
#pragma unroll
    for (int w = 0; w < 8; w++) s += sumA[w][tid];
    rsS[tid] = rsqrtf(s * (1.f / 128.f) + 1e-5f);
  }
  __syncthreads();
  float sc = ln_s[l * 128 + col], bb = ln_b[l * 128 + col];
#pragma unroll
  for (int reg = 0; reg < 4; reg++) {
    int rr = lhi * 4 + reg;
    int wrow = blockIdx.x * 16 + rr;
    zh[wrow * 256 + 128 + col] =
        (_Float16)((h[reg] - muS[rr]) * rsS[rr] * sc + bb);
  }
}

// ---------------- mean pool over nodes + 2-layer head (fp32)
__global__ __launch_bounds__(128) void k_head(const _Float16* __restrict__ zh,
    const float* __restrict__ Wh1, const float* __restrict__ bh1,
    const float* __restrict__ Wh2, const float* __restrict__ bh2,
    float* __restrict__ out) {
  __shared__ float ge[128], p1[128];
  int b = blockIdx.x, t = threadIdx.x;
  float s = 0.f;
  for (int n = 0; n < 128; n++) s += (float)zh[(b * 128 + n) * 256 + 128 + t];
  ge[t] = s * (1.f / 128.f);
  __syncthreads();
  float a = bh1[t];
  for (int k = 0; k < 128; k++) a += ge[k] * Wh1[k * 128 + t];
  p1[t] = fmaxf(a, 0.f);
  __syncthreads();
  float o = bh2[t];
  for (int k = 0; k < 128; k++) o += p1[k] * Wh2[k * 128 + t];
  out[b * 128 + t] = o;
}

extern "C" void kernel_launch(void* const* d_in, const int* in_sizes, int n_in,
                              void* d_out, int out_size, void* d_ws, size_t ws_size,
                              hipStream_t stream) {
  const int* x          = (const int*)d_in[0];
  const int* edge_attr  = (const int*)d_in[1];
  const int* edge_index = (const int*)d_in[2];
  const float* atom_emb = (const float*)d_in[4];
  const float* bond_emb = (const float*)d_in[5];
  const float* Wm1 = (const float*)d_in[6];
  const float* bm1 = (const float*)d_in[7];
  const float* Wm2 = (const float*)d_in[8];
  const float* bm2 = (const float*)d_in[9];
  const float* We  = (const float*)d_in[10];
  const float* be  = (const float*)d_in[11];
  const float* bg  = (const float*)d_in[13];   // Wg dead: graph_fts == 0
  const float* Wp1 = (const float*)d_in[14];
  const float* bp1 = (const float*)d_in[15];
  const float* Wp2 = (const float*)d_in[16];
  const float* bp2 = (const float*)d_in[17];
  const float* Wo1 = (const float*)d_in[18];
  const float* bo1 = (const float*)d_in[19];
  const float* Wo2 = (const float*)d_in[20];
  const float* bo2 = (const float*)d_in[21];
  const float* ln_s = (const float*)d_in[22];
  const float* ln_b = (const float*)d_in[23];
  const float* Wh1 = (const float*)d_in[24];
  const float* bh1 = (const float*)d_in[25];
  const float* Wh2 = (const float*)d_in[26];
  const float* bh2 = (const float*)d_in[27];
  float* out = (float*)d_out;

  // workspace carve-up (~15 MB)
  int* cnt       = (int*)d_ws;                  // 524288
  int* done      = cnt + SLOTS_;                // 16 (zeroed with cnt)
  int* basep     = done + 16;                   // 524288 (block-partial scan)
  int* pairbase  = basep + SLOTS_;              // 524288
  int* bsumA     = pairbase + SLOTS_;           // 2048
  int* bsumF     = bsumA + 2048;                // 2048
  int* pair_tot  = bsumF + 2048;                // 16
  int* erank     = pair_tot + 16;               // 65536
  int* sorted_e  = erank + EE_;                 // 65536
  int* pair_slot = sorted_e + EE_;              // 65536
  int* pair_off  = pair_slot + EE_;             // 65536
  int* pair_cnt  = pair_off + EE_;              // 65536
  unsigned* msgs_u = (unsigned*)(pair_cnt + EE_);   // 524288 u32
  _Float16* zh   = (_Float16*)(msgs_u + SLOTS_);    // 4096*256 f16
  _Float16* mm   = zh + NODES_ * 256;               // 4096*256 f16
  _Float16* bembWeh = mm + NODES_ * 256;            // 3*48*128 f16
  _Float16* Whf  = bembWeh + 3 * 48 * 128;          // 55296*8 f16

  hipMemsetAsync(cnt, 0, (SLOTS_ + 16) * sizeof(int), stream);

  k_pro<<<2592, 256, 0, stream>>>(x, atom_emb, zh, Wp1, Wp2, Wm1, Wm2, Wo1, Wo2,
                                  Whf, bond_emb, We, bembWeh, edge_index, cnt,
                                  erank);
  k_scanA2<<<SLOTS_ / 256, 256, 0, stream>>>(cnt, basep, pairbase, bsumA,
                                             bsumF, done);
  k_scanBSm12<<<3328, 256, 0, stream>>>(cnt, basep, pairbase, bsumA, bsumF,
                                        pair_tot, pair_slot, pair_off,
                                        pair_cnt, edge_index, erank, sorted_e,
                                        zh, Whf, bm1, bm2, mm, msgs_u);

  k_pairs<<<1024, 256, 0, stream>>>(mm, pair_slot, pair_off, pair_cnt,
                                    pair_tot, sorted_e, edge_attr, bembWeh,
                                    be, bg, Whf, bp1, bp2, msgs_u, 0);
  k_olnm12<<<NODES_ / 16, 512, 0, stream>>>(zh, msgs_u, Whf, bo1, bo2, ln_s,
                                            ln_b, bm1, bm2, mm, 0);
  k_pairs<<<1024, 256, 0, stream>>>(mm, pair_slot, pair_off, pair_cnt,
                                    pair_tot, sorted_e, edge_attr, bembWeh,
                                    be, bg, Whf, bp1, bp2, msgs_u, 1);
  k_olnm12<<<NODES_ / 16, 512, 0, stream>>>(zh, msgs_u, Whf, bo1, bo2, ln_s,
                                            ln_b, bm1, bm2, mm, 1);
  k_pairs<<<1024, 256, 0, stream>>>(mm, pair_slot, pair_off, pair_cnt,
                                    pair_tot, sorted_e, edge_attr, bembWeh,
                                    be, bg, Whf, bp1, bp2, msgs_u, 2);
  k_out_ln<<<NODES_ / 16, 512, 0, stream>>>(zh, msgs_u, Whf, bo1, bo2,
                                            ln_s, ln_b, 2);
  k_head<<<NB_, 128, 0, stream>>>(zh, Wh1, bh1, Wh2, bh2, out);
}

// Round 12
// 254.973 us; speedup vs baseline: 1.2171x; 1.2171x over previous
//
#include <hip/hip_runtime.h>
#include <hip/hip_bf16.h>

#define NB_ 32
#define LL_ 3
#define EE_ 65536
#define NODES_ 4096
#define SLOTS_ 524288   // NODES_ * 128
#define NEGV -1e9f

typedef _Float16 f16x8 __attribute__((ext_vector_type(8)));
typedef float f32x4 __attribute__((ext_vector_type(4)));

// order-preserving float->uint key (max over keys == max over floats)
__device__ __forceinline__ unsigned fkey(float f) {
  unsigned b = __float_as_uint(f);
  unsigned m = ((int)b >> 31) | 0x80000000u;
  return b ^ m;
}
__device__ __forceinline__ float funkey(unsigned k) {
  unsigned xm = (k & 0x80000000u) ? 0x80000000u : 0xFFFFFFFFu;
  return __uint_as_float(k ^ xm);
}

// ---------------- fused prologue: node_enc | wprep | bembWe | edge_count+rank
__global__ __launch_bounds__(256) void k_pro(const int* __restrict__ x,
    const float* __restrict__ atom_emb, _Float16* __restrict__ zh,
    const float* __restrict__ Wp1, const float* __restrict__ Wp2,
    const float* __restrict__ Wm1, const float* __restrict__ Wm2,
    const float* __restrict__ Wo1, const float* __restrict__ Wo2,
    _Float16* __restrict__ Whf,
    const float* __restrict__ bond_emb, const float* __restrict__ We,
    _Float16* __restrict__ bembWeh,
    const int* __restrict__ ei, int* __restrict__ cnt, int* __restrict__ erank) {
  int blk = blockIdx.x, tid = threadIdx.x;
  if (blk < 2048) {
    int v = blk * 2 + (tid >> 7), t = tid & 127;
    float acc = 0.f;
#pragma unroll
    for (int c = 0; c < 9; c++) {
      int xv = x[v * 9 + c];
      acc += atom_emb[(c * 128 + xv) * 128 + t];
    }
    zh[v * 256 + t] = (_Float16)acc;
    zh[v * 256 + 128 + t] = (_Float16)0.f;
  } else if (blk < 2264) {
    int gid = (blk - 2048) * 256 + tid;   // 0..55295
    int lane = gid & 63;
    int llo = lane & 15, lhi = lane >> 4;
    const float* W; int col, kbase;
    if (gid < 12288) {
      int mat = gid >> 11, pos = gid & 2047;
      int fr = pos >> 6; int ct = fr >> 2, kt = fr & 3;
      int lyr = mat >> 1, which = mat & 1;
      W = (which ? Wp2 : Wp1) + lyr * 16384;
      col = ct * 16 + llo; kbase = kt * 32 + lhi * 8;
    } else if (gid < 36864) {
      int q = gid - 12288;
      int lyr = q >> 13, r = q & 8191;
      int fr = r >> 6; int ct = fr >> 3, kt = fr & 7;
      col = ct * 16 + llo; kbase = kt * 32 + lhi * 8;
      if (col < 128) { W = Wm1 + lyr * 32768; }
      else { W = Wm2 + lyr * 32768; col -= 128; }
    } else {
      int q = gid - 36864;
      int lyr = q / 6144, r = q % 6144;
      int fr = r >> 6; int ct = fr / 12, kt = fr % 12;
      col = ct * 16 + llo; kbase = kt * 32 + lhi * 8;
      if (kbase < 256) { W = Wo1 + lyr * 32768; }
      else { W = Wo2 + lyr * 16384; kbase -= 256; }
    }
    f16x8 h;
#pragma unroll
    for (int e = 0; e < 8; e++) h[e] = (_Float16)W[(kbase + e) * 128 + col];
    ((f16x8*)Whf)[gid] = h;
  } else if (blk < 2336) {
    __shared__ float row[2][128];
    int rid = (blk - 2264) * 2 + (tid >> 7);   // 0..143
    int half = tid >> 7, c = tid & 127;
    int l = rid / 48, rr = rid % 48;
    row[half][c] = bond_emb[rr * 128 + c];
    __syncthreads();
    const float* W = We + l * 16384;
    float acc = 0.f;
    for (int k = 0; k < 128; k += 4) {
      acc += row[half][k] * W[k * 128 + c] +
             row[half][k + 1] * W[(k + 1) * 128 + c] +
             row[half][k + 2] * W[(k + 2) * 128 + c] +
             row[half][k + 3] * W[(k + 3) * 128 + c];
    }
    bembWeh[(l * 48 + rr) * 128 + c] = (_Float16)acc;
  } else {
    int e = (blk - 2336) * 256 + tid;
    int s = ei[e], d = ei[EE_ + e];
    int g = s >> 7, i = s & 127, j = d & 127;
    int slot = ((g << 7) + j) * 128 + i;   // receiver-major
    erank[e] = atomicAdd(&cnt[slot], 1);
  }
}

// ---------------- fused block-scan: edge-count scan + pair-flag scan
__global__ __launch_bounds__(256) void k_scanA(const int* __restrict__ cnt,
    int* __restrict__ basep, int* __restrict__ pairbase,
    int* __restrict__ bsumA, int* __restrict__ bsumF) {
  __shared__ int sA[256], sF[256];
  int t = threadIdx.x, gid = blockIdx.x * 256 + t;
  int v = cnt[gid];
  int f = v > 0 ? 1 : 0;
  sA[t] = v; sF[t] = f; __syncthreads();
  for (int st = 1; st < 256; st <<= 1) {
    int aA = sA[t], aF = sF[t];
    int bA = (t >= st) ? sA[t - st] : 0;
    int bF = (t >= st) ? sF[t - st] : 0;
    __syncthreads();
    sA[t] = aA + bA; sF[t] = aF + bF;
    __syncthreads();
  }
  basep[gid] = sA[t] - v;          // exclusive within block
  pairbase[gid] = sF[t] - f;
  if (t == 255) { bsumA[blockIdx.x] = sA[255]; bsumF[blockIdx.x] = sF[255]; }
}

// ---------------- scan of the 2048 block sums (block 0: A, block 1: F)
__global__ __launch_bounds__(256) void k_scan2d(int* __restrict__ bsumA,
                                                int* __restrict__ bsumF) {
  int* bsum = blockIdx.x ? bsumF : bsumA;
  __shared__ int s[256];
  int t = threadIdx.x;
  int v[8]; int tot = 0;
#pragma unroll
  for (int q = 0; q < 8; q++) { v[q] = bsum[t * 8 + q]; tot += v[q]; }
  s[t] = tot; __syncthreads();
  for (int st = 1; st < 256; st <<= 1) {
    int a = s[t]; int b = (t >= st) ? s[t - st] : 0;
    __syncthreads(); s[t] = a + b; __syncthreads();
  }
  int run = s[t] - tot;
#pragma unroll
  for (int q = 0; q < 8; q++) { int tmp = v[q]; bsum[t * 8 + q] = run; run += tmp; }
}

// ---------------- merged finalize: pair arrays | edge scatter | m12(l=0)+msgs
__global__ __launch_bounds__(256) void k_scanBSm12(const int* __restrict__ cnt,
    const int* __restrict__ basep, const int* __restrict__ pairbase,
    const int* __restrict__ bsumA, const int* __restrict__ bsumF,
    int* __restrict__ pair_total, int* __restrict__ pair_slot,
    int* __restrict__ pair_off, int* __restrict__ pair_cnt,
    const int* __restrict__ ei, const int* __restrict__ erank,
    int* __restrict__ sorted_e,
    const _Float16* __restrict__ zh, const _Float16* __restrict__ Whf,
    const float* __restrict__ bm1, const float* __restrict__ bm2,
    _Float16* __restrict__ mm, unsigned* __restrict__ msgs_u) {
  int blk = blockIdx.x, tid = threadIdx.x;
  if (blk < 2048) {
    int gid = blk * 256 + tid;
    int b = basep[gid] + bsumA[gid >> 8];
    int pb = pairbase[gid] + bsumF[gid >> 8];
    int c = cnt[gid];
    if (c > 0) {
      pair_slot[pb] = gid;
      pair_off[pb] = b;
      pair_cnt[pb] = c;
    }
    if (gid == SLOTS_ - 1) pair_total[0] = pb + (c > 0 ? 1 : 0);
  } else if (blk < 2304) {
    int e = (blk - 2048) * 256 + tid;
    int s = ei[e], d = ei[EE_ + e];
    int g = s >> 7, i = s & 127, j = d & 127;
    int slot = ((g << 7) + j) * 128 + i;
    int pos = basep[slot] + bsumA[slot >> 8] + erank[e];
    sorted_e[pos] = e;
  } else {
    int mblk = blk - 2304;                 // 0..1023: m12 for layer 0
    {  // msgs init for layer 0
      int g0 = mblk * 256 + tid;
      unsigned kneg = fkey(NEGV);
      msgs_u[g0] = kneg;
      msgs_u[g0 + 262144] = kneg;
    }
    int wv = tid >> 6, l64 = tid & 63;
    int llo = l64 & 15, lhi = l64 >> 4;
    int tile = mblk >> 2;
    int ct = (mblk & 3) * 4 + wv;          // 0..15
    int row = tile * 16 + llo;
    f16x8 a[8];
#pragma unroll
    for (int kt = 0; kt < 8; kt++)
      a[kt] = *(const f16x8*)(zh + row * 256 + kt * 32 + lhi * 8);
    const f16x8* Bf = (const f16x8*)Whf + 12288;   // layer 0
    int col = ct * 16 + llo;
    float bv = (col < 128) ? bm1[col] : bm2[col - 128];
    f32x4 acc = {bv, bv, bv, bv};
#pragma unroll
    for (int kt = 0; kt < 8; kt++)
      acc = __builtin_amdgcn_mfma_f32_16x16x32_f16(a[kt], Bf[(ct * 8 + kt) * 64 + l64], acc, 0, 0, 0);
#pragma unroll
    for (int reg = 0; reg < 4; reg++)
      mm[(tile * 16 + lhi * 4 + reg) * 256 + col] = (_Float16)acc[reg];
  }
}

// ---------------- MFMA pair MLP: 64 pairs/block, wave-shfl run scan
__global__ __launch_bounds__(256, 4) void k_pairs(
    const _Float16* __restrict__ mm,
    const int* __restrict__ pair_slot, const int* __restrict__ pair_off,
    const int* __restrict__ pair_cnt, const int* __restrict__ pair_total,
    const int* __restrict__ sorted_e, const int* __restrict__ edge_attr,
    const _Float16* __restrict__ bembWeh,
    const float* __restrict__ be, const float* __restrict__ bg,
    const _Float16* __restrict__ Whf,
    const float* __restrict__ bp1, const float* __restrict__ bp2,
    unsigned* __restrict__ msgs_u, int l) {
  __shared__ int s_slot[64], s_off[64], s_cnt[64], s_lrow[64];
  __shared__ int s_rid[16];
  __shared__ int s_nrecv;
  __shared__ unsigned Lmax[16 * 128];   // 8 KB receiver-tile max
  __shared__ _Float16 Uh[64 * 128];     // granule-XOR swizzled, 16 KB
  int P = pair_total[0];
  int pid0 = blockIdx.x * 64;
  if (pid0 >= P) return;
  int tid = threadIdx.x;
  {
    unsigned kneg = fkey(NEGV);
#pragma unroll
    for (int q = 0; q < 8; q++) Lmax[tid + q * 256] = kneg;
  }
  // wave 0 does the whole setup in-register (shfl), ONE block barrier total
  if (tid < 64) {
    int pid = pid0 + tid;
    bool va = pid < P;
    int slot = va ? pair_slot[pid] : -1;
    s_slot[tid] = slot;
    s_off[tid] = va ? pair_off[pid] : 0;
    s_cnt[tid] = va ? pair_cnt[pid] : 0;
    int r = slot >= 0 ? (slot >> 7) : -1;
    int ps = __shfl_up(slot, 1, 64);
    int pr = (tid == 0) ? -2 : (ps >= 0 ? (ps >> 7) : -1);
    int flag = (slot >= 0 && r != pr) ? 1 : 0;
    int val = flag;
#pragma unroll
    for (int d = 1; d < 64; d <<= 1) {
      int o = __shfl_up(val, d, 64);
      if (tid >= d) val += o;
    }
    int lr = val - 1;
    s_lrow[tid] = lr;
    if (flag && lr < 16) s_rid[lr] = r;
    if (tid == 63) s_nrecv = val;
  }
  __syncthreads();

  int l64 = tid & 63, wv = tid >> 6;
  int llo = l64 & 15, lhi = l64 >> 4;
  int p = wv * 16 + llo;
  int slot = s_slot[p];
  f16x8 a[4];
  if (slot >= 0) {
    int rr = slot >> 7, i = slot & 127, g = slot >> 14;
    int sn = (g << 7) + i;
    float t32[4][8];
#pragma unroll
    for (int kt = 0; kt < 4; kt++) {
      int c0 = kt * 32 + lhi * 8;
      f16x8 v1 = *(const f16x8*)(mm + sn * 256 + c0);         // m1[sender]
      f16x8 v2 = *(const f16x8*)(mm + rr * 256 + 128 + c0);   // m2[receiver]
      float4 e0 = *(const float4*)(be + l * 128 + c0);
      float4 e1 = *(const float4*)(be + l * 128 + c0 + 4);
      float4 g0 = *(const float4*)(bg + l * 128 + c0);
      float4 g1 = *(const float4*)(bg + l * 128 + c0 + 4);
      t32[kt][0] = (float)v1[0] + (float)v2[0] + e0.x + g0.x;
      t32[kt][1] = (float)v1[1] + (float)v2[1] + e0.y + g0.y;
      t32[kt][2] = (float)v1[2] + (float)v2[2] + e0.z + g0.z;
      t32[kt][3] = (float)v1[3] + (float)v2[3] + e0.w + g0.w;
      t32[kt][4] = (float)v1[4] + (float)v2[4] + e1.x + g1.x;
      t32[kt][5] = (float)v1[5] + (float)v2[5] + e1.y + g1.y;
      t32[kt][6] = (float)v1[6] + (float)v2[6] + e1.z + g1.z;
      t32[kt][7] = (float)v1[7] + (float)v2[7] + e1.w + g1.w;
    }
    int off = s_off[p], cn = s_cnt[p];
    for (int d = 0; d < cn; d++) {
      int eid = sorted_e[off + d];
      int a0 = edge_attr[eid * 3], a1 = edge_attr[eid * 3 + 1],
          a2 = edge_attr[eid * 3 + 2];
      const _Float16* r0 = bembWeh + (l * 48 + a0) * 128;
      const _Float16* r1 = bembWeh + (l * 48 + 16 + a1) * 128;
      const _Float16* r2 = bembWeh + (l * 48 + 32 + a2) * 128;
#pragma unroll
      for (int kt = 0; kt < 4; kt++) {
        int c0 = kt * 32 + lhi * 8;
        f16x8 x0 = *(const f16x8*)(r0 + c0);
        f16x8 x1 = *(const f16x8*)(r1 + c0);
        f16x8 x2 = *(const f16x8*)(r2 + c0);
#pragma unroll
        for (int e = 0; e < 8; e++)
          t32[kt][e] += (float)x0[e] + (float)x1[e] + (float)x2[e];
      }
    }
#pragma unroll
    for (int kt = 0; kt < 4; kt++)
#pragma unroll
      for (int e = 0; e < 8; e++) a[kt][e] = (_Float16)fmaxf(t32[kt][e], 0.f);
  } else {
#pragma unroll
    for (int kt = 0; kt < 4; kt++)
#pragma unroll
      for (int e = 0; e < 8; e++) a[kt][e] = (_Float16)0.f;
  }

  const f16x8* W1f = (const f16x8*)Whf + (l * 2) * 2048;
  const f16x8* W2f = (const f16x8*)Whf + (l * 2 + 1) * 2048;
  // ---- phase 1: U = relu(T @ Wp1 + bp1) -> swizzled f16 LDS
#pragma unroll
  for (int ct = 0; ct < 8; ct++) {
    int col = ct * 16 + llo;
    float b1 = bp1[l * 128 + col];
    f32x4 acc = {b1, b1, b1, b1};
#pragma unroll
    for (int kt = 0; kt < 4; kt++)
      acc = __builtin_amdgcn_mfma_f32_16x16x32_f16(a[kt], W1f[(ct * 4 + kt) * 64 + l64], acc, 0, 0, 0);
#pragma unroll
    for (int reg = 0; reg < 4; reg++) {
      int wrow = wv * 16 + lhi * 4 + reg;
      int sg = (2 * ct + (llo >> 3)) ^ (wrow & 15);
      Uh[wrow * 128 + sg * 8 + (llo & 7)] = (_Float16)fmaxf(acc[reg], 0.f);
    }
  }
  __syncthreads();
  // ---- phase 2: V = U @ Wp2 + bp2 ; LDS receiver-tile seg-max
  f16x8 a2[4];
  int arow = wv * 16 + llo;
#pragma unroll
  for (int kt = 0; kt < 4; kt++) {
    int sg = (kt * 4 + lhi) ^ (arow & 15);
    a2[kt] = *(const f16x8*)(Uh + arow * 128 + sg * 8);
  }
#pragma unroll
  for (int ct = 0; ct < 8; ct++) {
    int col = ct * 16 + llo;
    float b2 = bp2[l * 128 + col];
    f32x4 acc = {b2, b2, b2, b2};
#pragma unroll
    for (int kt = 0; kt < 4; kt++)
      acc = __builtin_amdgcn_mfma_f32_16x16x32_f16(a2[kt], W2f[(ct * 4 + kt) * 64 + l64], acc, 0, 0, 0);
    int prev_lr = -2, prev_rr = -1; float run = 0.f;
#pragma unroll
    for (int reg = 0; reg < 4; reg++) {
      int prow = wv * 16 + lhi * 4 + reg;
      int slot2 = s_slot[prow];
      if (slot2 < 0) continue;
      int lr = s_lrow[prow];
      float v = acc[reg];
      if (lr == prev_lr) {
        run = fmaxf(run, v);
      } else {
        if (prev_lr >= 0) {
          if (prev_lr < 16) atomicMax(&Lmax[prev_lr * 128 + col], fkey(run));
          else atomicMax(&msgs_u[prev_rr * 128 + col], fkey(run));
        }
        prev_lr = lr; prev_rr = slot2 >> 7; run = v;
      }
    }
    if (prev_lr >= 0) {
      if (prev_lr < 16) atomicMax(&Lmax[prev_lr * 128 + col], fkey(run));
      else atomicMax(&msgs_u[prev_rr * 128 + col], fkey(run));
    }
  }
  __syncthreads();
  // ---- flush receiver tile: one global atomic per (receiver, col) per block
  int nr = s_nrecv; if (nr > 16) nr = 16;
  for (int base = 0; base < nr; base += 2) {
    int lr = base + (tid >> 7);
    int col = tid & 127;
    if (lr < nr)
      atomicMax(&msgs_u[s_rid[lr] * 128 + col], Lmax[lr * 128 + col]);
  }
}

// ---------------- fused out_ln(l) + msgs re-init + m12(l+1)
__global__ __launch_bounds__(512, 2) void k_olnm12(_Float16* __restrict__ zh,
    unsigned* __restrict__ msgs_u, const _Float16* __restrict__ Whf,
    const float* __restrict__ bo1, const float* __restrict__ bo2,
    const float* __restrict__ ln_s, const float* __restrict__ ln_b,
    const float* __restrict__ bm1, const float* __restrict__ bm2,
    _Float16* __restrict__ mm, int l) {
  __shared__ float sumA[8][16];
  __shared__ float muS[16], rsS[16];
  __shared__ _Float16 hidT[16][132];    // +4 pad: kills stride-256B bank conflict
  int tid = threadIdx.x;
  int wv = tid >> 6, l64 = tid & 63;      // wv = ct (phase A)
  int llo = l64 & 15, lhi = l64 >> 4;
  int row = blockIdx.x * 16 + llo;
  f16x8 a[12];
#pragma unroll
  for (int kt = 0; kt < 8; kt++)
    a[kt] = *(const f16x8*)(zh + row * 256 + kt * 32 + lhi * 8);
#pragma unroll
  for (int kt = 8; kt < 12; kt++) {
    int k0 = (kt - 8) * 32 + lhi * 8;
    f16x8 h;
#pragma unroll
    for (int e = 0; e < 8; e++) {
      float v = funkey(msgs_u[row * 128 + k0 + e]);
      v = fmaxf(fminf(v, 60000.f), -60000.f);   // f16-safe (isolated-recv NEG)
      h[e] = (_Float16)v;
    }
    a[kt] = h;
  }
  const f16x8* Bo = (const f16x8*)Whf + 36864 + l * 6144;
  int ct = wv, col = ct * 16 + llo;
  float bv = bo1[l * 128 + col] + bo2[l * 128 + col];
  f32x4 acc = {bv, bv, bv, bv};
#pragma unroll
  for (int kt = 0; kt < 12; kt++)
    acc = __builtin_amdgcn_mfma_f32_16x16x32_f16(a[kt], Bo[(ct * 12 + kt) * 64 + l64], acc, 0, 0, 0);
  float h[4];
#pragma unroll
  for (int reg = 0; reg < 4; reg++) h[reg] = fmaxf(acc[reg], 0.f);
  // mean: reduce over llo lanes, then across 8 ct-waves via LDS
#pragma unroll
  for (int reg = 0; reg < 4; reg++) {
    float s = h[reg];
    s += __shfl_xor(s, 1, 64); s += __shfl_xor(s, 2, 64);
    s += __shfl_xor(s, 4, 64); s += __shfl_xor(s, 8, 64);
    if (llo == 0) sumA[wv][lhi * 4 + reg] = s;
  }
  __syncthreads();
  if (tid < 16) {
    float s = 0.f;
#pragma unroll
    for (int w = 0; w < 8; w++) s += sumA[w][tid];
    muS[tid] = s * (1.f / 128.f);
  }
  __syncthreads();
#pragma unroll
  for (int reg = 0; reg < 4; reg++) {
    float d = h[reg] - muS[lhi * 4 + reg];
    float s = d * d;
    s += __shfl_xor(s, 1, 64); s += __shfl_xor(s, 2, 64);
    s += __shfl_xor(s, 4, 64); s += __shfl_xor(s, 8, 64);
    if (llo == 0) sumA[wv][lhi * 4 + reg] = s;
  }
  __syncthreads();
  if (tid < 16) {
    float s = 0.f;
#pragma unroll
    for (int w = 0; w < 8; w++) s += sumA[w][tid];
    rsS[tid] = rsqrtf(s * (1.f / 128.f) + 1e-5f);
  }
  __syncthreads();
  float sc = ln_s[l * 128 + col], bb = ln_b[l * 128 + col];
#pragma unroll
  for (int reg = 0; reg < 4; reg++) {
    int rr = lhi * 4 + reg;
    int wrow = blockIdx.x * 16 + rr;
    _Float16 hh = (_Float16)((h[reg] - muS[rr]) * rsS[rr] * sc + bb);
    zh[wrow * 256 + 128 + col] = hh;
    hidT[rr][col] = hh;
  }
  {  // msgs re-init for this block's 16 rows (all reads done)
    unsigned kneg = fkey(NEGV);
    int base = blockIdx.x * 2048 + tid;
    msgs_u[base] = kneg;
    msgs_u[base + 512] = kneg;
    msgs_u[base + 1024] = kneg;
    msgs_u[base + 1536] = kneg;
  }
  __syncthreads();
  // ---- phase B: m12 for layer l+1 on the same 16 rows
  f16x8 b[4];
#pragma unroll
  for (int kt = 0; kt < 4; kt++)
    b[kt] = *(const f16x8*)(&hidT[llo][kt * 32 + lhi * 8]);
  const f16x8* Bm = (const f16x8*)Whf + 12288 + (l + 1) * 8192;
#pragma unroll
  for (int q = 0; q < 2; q++) {
    int ct2 = wv + q * 8;     // 0..15
    int col2 = ct2 * 16 + llo;
    float bv2 = (col2 < 128) ? bm1[(l + 1) * 128 + col2]
                             : bm2[(l + 1) * 128 + col2 - 128];
    f32x4 acc2 = {bv2, bv2, bv2, bv2};
#pragma unroll
    for (int kt = 0; kt < 4; kt++)
      acc2 = __builtin_amdgcn_mfma_f32_16x16x32_f16(a[kt], Bm[(ct2 * 8 + kt) * 64 + l64], acc2, 0, 0, 0);
#pragma unroll
    for (int kt = 0; kt < 4; kt++)
      acc2 = __builtin_amdgcn_mfma_f32_16x16x32_f16(b[kt], Bm[(ct2 * 8 + 4 + kt) * 64 + l64], acc2, 0, 0, 0);
#pragma unroll
    for (int reg = 0; reg < 4; reg++)
      mm[(blockIdx.x * 16 + lhi * 4 + reg) * 256 + col2] = (_Float16)acc2[reg];
  }
}

// ---------------- final out_ln (layer 2): h + LN -> zh hidden half
__global__ __launch_bounds__(512, 2) void k_out_ln(_Float16* __restrict__ zh,
    const unsigned* __restrict__ msgs_u, const _Float16* __restrict__ Whf,
    const float* __restrict__ bo1, const float* __restrict__ bo2,
    const float* __restrict__ ln_s, const float* __restrict__ ln_b, int l) {
  __shared__ float sumA[8][16];
  __shared__ float muS[16], rsS[16];
  int tid = threadIdx.x;
  int wv = tid >> 6, l64 = tid & 63;      // wv = ct
  int llo = l64 & 15, lhi = l64 >> 4;
  int row = blockIdx.x * 16 + llo;
  f16x8 a[12];
#pragma unroll
  for (int kt = 0; kt < 8; kt++)
    a[kt] = *(const f16x8*)(zh + row * 256 + kt * 32 + lhi * 8);
#pragma unroll
  for (int kt = 8; kt < 12; kt++) {
    int k0 = (kt - 8) * 32 + lhi * 8;
    f16x8 h;
#pragma unroll
    for (int e = 0; e < 8; e++) {
      float v = funkey(msgs_u[row * 128 + k0 + e]);
      v = fmaxf(fminf(v, 60000.f), -60000.f);
      h[e] = (_Float16)v;
    }
    a[kt] = h;
  }
  const f16x8* Bf = (const f16x8*)Whf + 36864 + l * 6144;
  int ct = wv, col = ct * 16 + llo;
  float bv = bo1[l * 128 + col] + bo2[l * 128 + col];
  f32x4 acc = {bv, bv, bv, bv};
#pragma unroll
  for (int kt = 0; kt < 12; kt++)
    acc = __builtin_amdgcn_mfma_f32_16x16x32_f16(a[kt], Bf[(ct * 12 + kt) * 64 + l64], acc, 0, 0, 0);
  float h[4];
#pragma unroll
  for (int reg = 0; reg < 4; reg++) h[reg] = fmaxf(acc[reg], 0.f);
#pragma unroll
  for (int reg = 0; reg < 4; reg++) {
    float s = h[reg];
    s += __shfl_xor(s, 1, 64); s += __shfl_xor(s, 2, 64);
    s += __shfl_xor(s, 4, 64); s += __shfl_xor(s, 8, 64);
    if (llo == 0) sumA[wv][lhi * 4 + reg] = s;
  }
  __syncthreads();
  if (tid < 16) {
    float s = 0.f;
#pragma unroll
    for (int w = 0; w < 8; w++) s += sumA[w][tid];
    muS[tid] = s * (1.f / 128.f);
  }
  __syncthreads();
#pragma unroll
  for (int reg = 0; reg < 4; reg++) {
    float d = h[reg] - muS[lhi * 4 + reg];
    float s = d * d;
    s += __shfl_xor(s, 1, 64); s += __shfl_xor(s, 2, 64);
    s += __shfl_xor(s, 4, 64); s += __shfl_xor(s, 8, 64);
    if (llo == 0) sumA[wv][lhi * 4 + reg] = s;
  }
  __syncthreads();
  if (tid < 16) {
    float s = 0.f;
#pragma unroll
    for (int w = 0; w < 8; w++) s += sumA[w][tid];
    rsS[tid] = rsqrtf(s * (1.f / 128.f) + 1e-5f);
  }
  __syncthreads();
  float sc = ln_s[l * 128 + col], bb = ln_b[l * 128 + col];
#pragma unroll
  for (int reg = 0; reg < 4; reg++) {
    int rr = lhi * 4 + reg;
    int wrow = blockIdx.x * 16 + rr;
    zh[wrow * 256 + 128 + col] =
        (_Float16)((h[reg] - muS[rr]) * rsS[rr] * sc + bb);
  }
}

// ---------------- mean pool over nodes + 2-layer head (fp32)
__global__ __launch_bounds__(128) void k_head(const _Float16* __restrict__ zh,
    const float* __restrict__ Wh1, const float* __restrict__ bh1,
    const float* __restrict__ Wh2, const float* __restrict__ bh2,
    float* __restrict__ out) {
  __shared__ float ge[128], p1[128];
  int b = blockIdx.x, t = threadIdx.x;
  float s = 0.f;
  for (int n = 0; n < 128; n++) s += (float)zh[(b * 128 + n) * 256 + 128 + t];
  ge[t] = s * (1.f / 128.f);
  __syncthreads();
  float a = bh1[t];
  for (int k = 0; k < 128; k++) a += ge[k] * Wh1[k * 128 + t];
  p1[t] = fmaxf(a, 0.f);
  __syncthreads();
  float o = bh2[t];
  for (int k = 0; k < 128; k++) o += p1[k] * Wh2[k * 128 + t];
  out[b * 128 + t] = o;
}

extern "C" void kernel_launch(void* const* d_in, const int* in_sizes, int n_in,
                              void* d_out, int out_size, void* d_ws, size_t ws_size,
                              hipStream_t stream) {
  const int* x          = (const int*)d_in[0];
  const int* edge_attr  = (const int*)d_in[1];
  const int* edge_index = (const int*)d_in[2];
  const float* atom_emb = (const float*)d_in[4];
  const float* bond_emb = (const float*)d_in[5];
  const float* Wm1 = (const float*)d_in[6];
  const float* bm1 = (const float*)d_in[7];
  const float* Wm2 = (const float*)d_in[8];
  const float* bm2 = (const float*)d_in[9];
  const float* We  = (const float*)d_in[10];
  const float* be  = (const float*)d_in[11];
  const float* bg  = (const float*)d_in[13];   // Wg dead: graph_fts == 0
  const float* Wp1 = (const float*)d_in[14];
  const float* bp1 = (const float*)d_in[15];
  const float* Wp2 = (const float*)d_in[16];
  const float* bp2 = (const float*)d_in[17];
  const float* Wo1 = (const float*)d_in[18];
  const float* bo1 = (const float*)d_in[19];
  const float* Wo2 = (const float*)d_in[20];
  const float* bo2 = (const float*)d_in[21];
  const float* ln_s = (const float*)d_in[22];
  const float* ln_b = (const float*)d_in[23];
  const float* Wh1 = (const float*)d_in[24];
  const float* bh1 = (const float*)d_in[25];
  const float* Wh2 = (const float*)d_in[26];
  const float* bh2 = (const float*)d_in[27];
  float* out = (float*)d_out;

  // workspace carve-up (~15 MB)
  int* cnt       = (int*)d_ws;                  // 524288
  int* basep     = cnt + SLOTS_;                // 524288 (block-partial scan)
  int* pairbase  = basep + SLOTS_;              // 524288
  int* bsumA     = pairbase + SLOTS_;           // 2048
  int* bsumF     = bsumA + 2048;                // 2048
  int* pair_tot  = bsumF + 2048;                // 16
  int* erank     = pair_tot + 16;               // 65536
  int* sorted_e  = erank + EE_;                 // 65536
  int* pair_slot = sorted_e + EE_;              // 65536
  int* pair_off  = pair_slot + EE_;             // 65536
  int* pair_cnt  = pair_off + EE_;              // 65536
  unsigned* msgs_u = (unsigned*)(pair_cnt + EE_);   // 524288 u32
  _Float16* zh   = (_Float16*)(msgs_u + SLOTS_);    // 4096*256 f16
  _Float16* mm   = zh + NODES_ * 256;               // 4096*256 f16
  _Float16* bembWeh = mm + NODES_ * 256;            // 3*48*128 f16
  _Float16* Whf  = bembWeh + 3 * 48 * 128;          // 55296*8 f16

  hipMemsetAsync(cnt, 0, SLOTS_ * sizeof(int), stream);

  k_pro<<<2592, 256, 0, stream>>>(x, atom_emb, zh, Wp1, Wp2, Wm1, Wm2, Wo1, Wo2,
                                  Whf, bond_emb, We, bembWeh, edge_index, cnt,
                                  erank);
  k_scanA<<<SLOTS_ / 256, 256, 0, stream>>>(cnt, basep, pairbase, bsumA, bsumF);
  k_scan2d<<<2, 256, 0, stream>>>(bsumA, bsumF);
  k_scanBSm12<<<3328, 256, 0, stream>>>(cnt, basep, pairbase, bsumA, bsumF,
                                        pair_tot, pair_slot, pair_off,
                                        pair_cnt, edge_index, erank, sorted_e,
                                        zh, Whf, bm1, bm2, mm, msgs_u);

  k_pairs<<<1024, 256, 0, stream>>>(mm, pair_slot, pair_off, pair_cnt,
                                    pair_tot, sorted_e, edge_attr, bembWeh,
                                    be, bg, Whf, bp1, bp2, msgs_u, 0);
  k_olnm12<<<NODES_ / 16, 512, 0, stream>>>(zh, msgs_u, Whf, bo1, bo2, ln_s,
                                            ln_b, bm1, bm2, mm, 0);
  k_pairs<<<1024, 256, 0, stream>>>(mm, pair_slot, pair_off, pair_cnt,
                                    pair_tot, sorted_e, edge_attr, bembWeh,
                                    be, bg, Whf, bp1, bp2, msgs_u, 1);
  k_olnm12<<<NODES_ / 16, 512, 0, stream>>>(zh, msgs_u, Whf, bo1, bo2, ln_s,
                                            ln_b, bm1, bm2, mm, 1);
  k_pairs<<<1024, 256, 0, stream>>>(mm, pair_slot, pair_off, pair_cnt,
                                    pair_tot, sorted_e, edge_attr, bembWeh,
                                    be, bg, Whf, bp1, bp2, msgs_u, 2);
  k_out_ln<<<NODES_ / 16, 512, 0, stream>>>(zh, msgs_u, Whf, bo1, bo2,
                                            ln_s, ln_b, 2);
  k_head<<<NB_, 128, 0, stream>>>(zh, Wh1, bh1, Wh2, bh2, out);
}